// Round 5
// baseline (457.815 us; speedup 1.0000x reference)
//
#include <hip/hip_runtime.h>
#include <hip/hip_bf16.h>

typedef __bf16 bf16x8 __attribute__((ext_vector_type(8)));
typedef __bf16 bf16x4 __attribute__((ext_vector_type(4)));
typedef float  f32x4  __attribute__((ext_vector_type(4)));

// Problem constants: B=32, N=4096, H=256, TDIM=128, K=2, R=2

// ---- workspace byte offsets ----
static constexpr size_t WS_A     = 0;                   // 5 f32 combine coeffs
static constexpr size_t WS_TOUT  = 1024;                // t_out [32,256] f32
static constexpr size_t WS_Z1    = 65536;               // z1..z4 [32,4096] f32 each
static constexpr size_t WS_ZSTR  = 524288;
static constexpr size_t WS_H0    = WS_Z1 + 4 * WS_ZSTR; // h0 [32,256] f32 (atomic acc)
static constexpr size_t WS_G2F   = WS_H0 + 32768;       // g2 [32,4096] f32
static constexpr size_t WS_UB    = WS_G2F + 524288;     // u [32,256] bf16
static constexpr size_t WS_WMAPT = 2752512;             // w_map^T [256,4096] bf16
static constexpr size_t WS_WO2T  = WS_WMAPT + 2097152;  // w_o2^T [4096,256] bf16
static constexpr size_t WS_LBF   = 8388608;             // L bf16 [4096,4096] (32 MB)

__device__ __forceinline__ f32x4 mfma16(bf16x8 a, bf16x8 b, f32x4 c) {
    return __builtin_amdgcn_mfma_f32_16x16x32_bf16(a, b, c, 0, 0, 0);
}

__device__ __forceinline__ bf16x8 pack8(f32x4 lo, f32x4 hi) {
    bf16x8 r;
    r[0] = (__bf16)lo[0]; r[1] = (__bf16)lo[1]; r[2] = (__bf16)lo[2]; r[3] = (__bf16)lo[3];
    r[4] = (__bf16)hi[0]; r[5] = (__bf16)hi[1]; r[6] = (__bf16)hi[2]; r[7] = (__bf16)hi[3];
    return r;
}

__device__ __forceinline__ bf16x8 cvt8(const float* p) {
    return pack8(*(const f32x4*)p, *(const f32x4*)(p + 4));
}

__device__ __forceinline__ float silu_f(float x) { return x / (1.0f + __expf(-x)); }

// y[col] = sum_j zs[j] * W[j*256+col], K = NST*16, 16-deep double-buffered prefetch.
template <int NST>
__device__ __forceinline__ float dotW(const float* __restrict__ W,
                                      const float* __restrict__ zs, int col) {
    float wb[2][16];
#pragma unroll
    for (int u = 0; u < 16; ++u) wb[0][u] = W[u * 256 + col];
    float a0 = 0, a1 = 0, a2 = 0, a3 = 0;
#pragma unroll
    for (int g = 0; g < NST; ++g) {
        const int cur = g & 1, nxt = cur ^ 1;
        if (g < NST - 1) {
#pragma unroll
            for (int u = 0; u < 16; ++u) wb[nxt][u] = W[((g + 1) * 16 + u) * 256 + col];
        }
        const float* z = zs + g * 16;
#pragma unroll
        for (int u = 0; u < 16; u += 4) {
            a0 += z[u]     * wb[cur][u];
            a1 += z[u + 1] * wb[cur][u + 1];
            a2 += z[u + 2] * wb[cur][u + 2];
            a3 += z[u + 3] * wb[cur][u + 3];
        }
    }
    return (a0 + a1) + (a2 + a3);
}

// 32x32 tile transpose f32 -> bf16 via LDS
__device__ __forceinline__ void transpose_tile(const float* __restrict__ src, int sstride,
                                               __bf16* __restrict__ dst, int dstride,
                                               int r0, int c0, float* sh, int tid) {
    const int r = tid >> 3, cg = (tid & 7) * 4;
    f32x4 v = *(const f32x4*)(src + (size_t)(r0 + r) * sstride + c0 + cg);
    sh[r * 33 + cg + 0] = v[0];
    sh[r * 33 + cg + 1] = v[1];
    sh[r * 33 + cg + 2] = v[2];
    sh[r * 33 + cg + 3] = v[3];
    __syncthreads();
    bf16x4 o;
    o[0] = (__bf16)sh[(cg + 0) * 33 + r];
    o[1] = (__bf16)sh[(cg + 1) * 33 + r];
    o[2] = (__bf16)sh[(cg + 2) * 33 + r];
    o[3] = (__bf16)sh[(cg + 3) * 33 + r];
    *(bf16x4*)(dst + (size_t)(c0 + r) * dstride + r0 + cg) = o;
}

// prep grid ranges
static constexpr int PG_LCVT  = 8192;              // L f32 -> bf16 (2048 elem/block)
static constexpr int PG_COEF  = PG_LCVT;           // == 8192
static constexpr int PG_TMLP  = PG_COEF + 1;       // 8193..8224
static constexpr int PG_ZERO  = PG_TMLP + 32;      // 8225..8744 (520)
static constexpr int PG_WMAP  = PG_ZERO + 520;     // 8745..9768 (1024)
static constexpr int PG_WO2   = PG_WMAP + 1024;    // 9769..10792 (1024)
static constexpr int PG_TOTAL = PG_WO2 + 1024;     // 10793

// Node 1: L->bf16 convert, coeffs, time-MLP, zero accumulators, weight transposes.
__global__ __launch_bounds__(256) void prep_kernel(
    const float* __restrict__ t, const float* __restrict__ L,
    const float* __restrict__ w_g1, const float* __restrict__ w_g2,
    const float* __restrict__ w_t1, const float* __restrict__ b_t1,
    const float* __restrict__ w_t2, const float* __restrict__ b_t2,
    const float* __restrict__ w_map, const float* __restrict__ w_o2,
    char* __restrict__ ws)
{
    __shared__ float sh[1056];
    const int bi = blockIdx.x, tid = threadIdx.x;
    if (bi < PG_LCVT) {
        // convert 64 MB f32 L -> 32 MB bf16 (same layout)
        const size_t base = (size_t)bi * 2048 + (size_t)tid * 8;
        *(bf16x8*)((__bf16*)(ws + WS_LBF) + base) = cvt8(L + base);
    } else if (bi == PG_COEF) {
        if (tid < 9) {
            const int k1 = tid / 3, k2 = tid % 3;
            float s = 0.f;
            for (int h = 0; h < 256; ++h) s += w_g1[h * 3 + k1] * w_g2[h * 3 + k2];
            sh[tid] = s;
        }
        __syncthreads();
        if (tid == 0) {
            float* a = (float*)(ws + WS_A);
            a[0] = sh[0];
            a[1] = sh[1] + sh[3];
            a[2] = sh[2] + sh[4] + sh[6];
            a[3] = sh[5] + sh[7];
            a[4] = sh[8];
        }
    } else if (bi < PG_ZERO) {
        const int b = bi - PG_TMLP;
        float* t_out = (float*)(ws + WS_TOUT);
        if (tid < 64) {
            float fr = __expf(-9.210340371976184f * (float)tid * (1.0f / 64.0f));
            float ang = t[b] * fr;
            sh[tid]      = __cosf(ang);
            sh[64 + tid] = __sinf(ang);
        }
        __syncthreads();
        float h1 = silu_f(b_t1[tid] + dotW<8>(w_t1, sh, tid));
        sh[128 + tid] = h1;
        __syncthreads();
        t_out[b * 256 + tid] = b_t2[tid] + dotW<16>(w_t2, sh + 128, tid);
    } else if (bi < PG_WMAP) {
        f32x4* p = (f32x4*)(ws + WS_Z1 + (size_t)(bi - PG_ZERO) * 4096);
        f32x4 z = {0.f, 0.f, 0.f, 0.f};
        p[tid] = z;
    } else if (bi < PG_WO2) {
        const int ti = bi - PG_WMAP;
        transpose_tile(w_map, 256, (__bf16*)(ws + WS_WMAPT), 4096,
                       (ti >> 3) * 32, (ti & 7) * 32, sh, tid);
    } else {
        const int ti = bi - PG_WO2;
        transpose_tile(w_o2, 4096, (__bf16*)(ws + WS_WO2T), 256,
                       (ti & 7) * 32, (ti >> 3) * 32, sh, tid);
    }
}

// Nodes 2-5: zout[b,m] += sum_n L[m,n] * zin[b,n].  z layout [32, 4096].
// Grid 1024 = 128 mt x 8 kc (bi = mt*8 + kc; bi%8 == kc -> same-kc blocks share
// an XCD; that XCD's L-bf16 column slice = 4096 x 512 x 2B = 4 MB = its L2).
// 4 waves x 128-k; software-pipelined loads; LDS reduce; 4 atomics/thread.
__global__ __launch_bounds__(256, 4) void hop_kernel(
    const __bf16* __restrict__ Lb, const float* __restrict__ zin,
    float* __restrict__ zout)
{
    __shared__ float red[4][32][33];
    const int bi = blockIdx.x, tid = threadIdx.x;
    const int wave = tid >> 6, lane = tid & 63;
    const int l15 = lane & 15, q = lane >> 4;
    const int mt = bi >> 3, kc = bi & 7;
    const int m0 = mt * 32;
    const int kbase = kc * 512 + wave * 128;

    const __bf16* ap0 = Lb + (size_t)(m0 + l15) * 4096;
    const __bf16* ap1 = ap0 + (size_t)16 * 4096;
    const float*  b0p = zin + (size_t)l15 * 4096;
    const float*  b1p = zin + (size_t)(l15 + 16) * 4096;

    int k = kbase + q * 8;
    bf16x8 a0 = *(const bf16x8*)(ap0 + k);
    bf16x8 a1 = *(const bf16x8*)(ap1 + k);
    f32x4 b0lo = *(const f32x4*)(b0p + k), b0hi = *(const f32x4*)(b0p + k + 4);
    f32x4 b1lo = *(const f32x4*)(b1p + k), b1hi = *(const f32x4*)(b1p + k + 4);

    f32x4 acc00 = {0,0,0,0}, acc01 = {0,0,0,0}, acc10 = {0,0,0,0}, acc11 = {0,0,0,0};
#pragma unroll
    for (int ks = 0; ks < 4; ++ks) {
        bf16x8 na0, na1; f32x4 nb0lo, nb0hi, nb1lo, nb1hi;
        if (ks < 3) {
            const int kn = k + 32;
            na0   = *(const bf16x8*)(ap0 + kn);
            na1   = *(const bf16x8*)(ap1 + kn);
            nb0lo = *(const f32x4*)(b0p + kn);
            nb0hi = *(const f32x4*)(b0p + kn + 4);
            nb1lo = *(const f32x4*)(b1p + kn);
            nb1hi = *(const f32x4*)(b1p + kn + 4);
        }
        bf16x8 b0 = pack8(b0lo, b0hi);
        bf16x8 b1 = pack8(b1lo, b1hi);
        acc00 = mfma16(a0, b0, acc00);
        acc01 = mfma16(a0, b1, acc01);
        acc10 = mfma16(a1, b0, acc10);
        acc11 = mfma16(a1, b1, acc11);
        a0 = na0; a1 = na1;
        b0lo = nb0lo; b0hi = nb0hi; b1lo = nb1lo; b1hi = nb1hi;
        k += 32;
    }
    // C/D layout: col = lane&15 (b-dim), row = q*4+reg (m-dim)
#pragma unroll
    for (int r = 0; r < 4; ++r) {
        const int mr = q * 4 + r;
        red[wave][mr][l15]           = acc00[r];
        red[wave][mr][l15 + 16]      = acc01[r];
        red[wave][16 + mr][l15]      = acc10[r];
        red[wave][16 + mr][l15 + 16] = acc11[r];
    }
    __syncthreads();
#pragma unroll
    for (int j = 0; j < 4; ++j) {
        const int o = tid + 256 * j;
        const int bcol = o & 31, m = o >> 5;
        float v = red[0][m][bcol] + red[1][m][bcol]
                + red[2][m][bcol] + red[3][m][bcol];
        atomicAdd(zout + (size_t)bcol * 4096 + m0 + m, v);
    }
}

// Node 6: g2 = a0*x + a1*z1 + a2*z2 + a3*z3 + a4*z4
__global__ __launch_bounds__(256) void combine_kernel(
    const float* __restrict__ x,
    const float* __restrict__ z1, const float* __restrict__ z2,
    const float* __restrict__ z3, const float* __restrict__ z4,
    const float* __restrict__ a, float* __restrict__ g2)
{
    const int i = blockIdx.x * 256 + threadIdx.x;
    const float a0 = a[0], a1 = a[1], a2 = a[2], a3 = a[3], a4 = a[4];
    f32x4 r = a0 * ((const f32x4*)x)[i] + a1 * ((const f32x4*)z1)[i]
            + a2 * ((const f32x4*)z2)[i] + a3 * ((const f32x4*)z3)[i]
            + a4 * ((const f32x4*)z4)[i];
    ((f32x4*)g2)[i] = r;
}

// Node 7: h0[b,h] += sum_n g2[b,n] * w_map[n,h]   (grid 128: btile x hp x 8 kc)
__global__ __launch_bounds__(256) void map_gemm_kernel(
    const float* __restrict__ g2, const __bf16* __restrict__ w_mapT,
    float* __restrict__ h0)
{
    __shared__ float red[4][16][32];
    const int bi = blockIdx.x, tid = threadIdx.x;
    const int wave = tid >> 6, lane = tid & 63;
    const int l15 = lane & 15, q = lane >> 4;
    const int btile = bi & 1;
    const int hp = (bi >> 1) & 7;
    const int kc = bi >> 4;                 // 0..7
    const int kbase = kc * 512 + wave * 128;

    const float*  ap  = g2 + (size_t)(btile * 16 + l15) * 4096;
    const __bf16* bp0 = w_mapT + (size_t)(hp * 32 + l15) * 4096;
    const __bf16* bp1 = w_mapT + (size_t)(hp * 32 + 16 + l15) * 4096;

    f32x4 acc0 = {0,0,0,0}, acc1 = {0,0,0,0};
#pragma unroll
    for (int ks = 0; ks < 4; ++ks) {
        const int k = kbase + ks * 32 + q * 8;
        bf16x8 a  = cvt8(ap + k);
        bf16x8 b0 = *(const bf16x8*)(bp0 + k);
        bf16x8 b1 = *(const bf16x8*)(bp1 + k);
        acc0 = mfma16(a, b0, acc0);
        acc1 = mfma16(a, b1, acc1);
    }
#pragma unroll
    for (int r = 0; r < 4; ++r) {
        red[wave][q * 4 + r][l15]      = acc0[r];
        red[wave][q * 4 + r][l15 + 16] = acc1[r];
    }
    __syncthreads();
    const int b_l = tid >> 4, hl = tid & 15;
#pragma unroll
    for (int s = 0; s < 2; ++s) {
        const int h_l = hl + s * 16;
        float v = red[0][b_l][h_l] + red[1][b_l][h_l] + red[2][b_l][h_l] + red[3][b_l][h_l];
        atomicAdd(h0 + (size_t)(btile * 16 + b_l) * 256 + hp * 32 + h_l, v);
    }
}

// Node 8: ResNet_FC + head to u (bf16). 1024 thr: col=tid&255, kg=tid>>8.
__global__ __launch_bounds__(1024) void resnet_kernel(
    const float* __restrict__ h0, const float* __restrict__ b_map,
    const float* __restrict__ res_w, const float* __restrict__ res_b,
    const float* __restrict__ t_out, const float* __restrict__ w_o1,
    const float* __restrict__ b_o1, __bf16* __restrict__ u_b)
{
    __shared__ float zs[256];
    __shared__ float part[4][256];
    const int b = blockIdx.x, tid = threadIdx.x;
    const int col = tid & 255, kg = tid >> 8;

    float hv = 0.f;
    if (kg == 0) {
        hv = h0[b * 256 + col] + b_map[col];
        zs[col] = hv;
    }
    __syncthreads();

#pragma unroll
    for (int r = 0; r < 2; ++r) {
        for (int i = 0; i < 3; ++i) {
            part[kg][col] = dotW<4>(res_w + ((size_t)(r * 3 + i) << 16) + (size_t)kg * 64 * 256,
                                    zs + kg * 64, col);
            __syncthreads();
            if (kg == 0) {
                zs[col] = silu_f(res_b[(r * 3 + i) * 256 + col]
                                 + part[0][col] + part[1][col] + part[2][col] + part[3][col]);
            }
            __syncthreads();
        }
        if (kg == 0) {
            hv = (hv + zs[col]) * 0.70710678118654752f;
            zs[col] = hv;
        }
        __syncthreads();
    }

    if (kg == 0) zs[col] = hv + t_out[b * 256 + col];
    __syncthreads();
    part[kg][col] = dotW<4>(w_o1 + (size_t)kg * 64 * 256, zs + kg * 64, col);
    __syncthreads();
    if (kg == 0) {
        u_b[b * 256 + col] = (__bf16)silu_f(b_o1[col]
            + part[0][col] + part[1][col] + part[2][col] + part[3][col]);
    }
}

// Node 9: out[b,n] = sum_h u[b,h] * w_o2[h,n] + b_o2[n]   (K=256, full-K per wave)
__global__ __launch_bounds__(256) void out_gemm_kernel(
    const __bf16* __restrict__ u_b, const __bf16* __restrict__ w_o2T,
    const float* __restrict__ b_o2, float* __restrict__ out)
{
    const int tid = threadIdx.x;
    const int wave = tid >> 6, lane = tid & 63;
    const int l15 = lane & 15, q = lane >> 4;
    const int g = blockIdx.x * 4 + wave;
    const int btile = g & 1;
    const int n0 = (g >> 1) * 32;

    const __bf16* ap  = u_b + (size_t)(btile * 16 + l15) * 256;
    const __bf16* bp0 = w_o2T + (size_t)(n0 + l15) * 256;
    const __bf16* bp1 = w_o2T + (size_t)(n0 + 16 + l15) * 256;

    f32x4 acc0 = {0,0,0,0}, acc1 = {0,0,0,0};
#pragma unroll
    for (int ks = 0; ks < 8; ++ks) {
        const int k = ks * 32 + q * 8;
        bf16x8 a  = *(const bf16x8*)(ap + k);
        bf16x8 b0 = *(const bf16x8*)(bp0 + k);
        bf16x8 b1 = *(const bf16x8*)(bp1 + k);
        acc0 = mfma16(a, b0, acc0);
        acc1 = mfma16(a, b1, acc1);
    }
    const int row = btile * 16 + q * 4;
    const int na = n0 + l15, nb = n0 + 16 + l15;
#pragma unroll
    for (int r = 0; r < 4; ++r) {
        out[(size_t)(row + r) * 4096 + na] = acc0[r] + b_o2[na];
        out[(size_t)(row + r) * 4096 + nb] = acc1[r] + b_o2[nb];
    }
}

extern "C" void kernel_launch(void* const* d_in, const int* in_sizes, int n_in,
                              void* d_out, int out_size, void* d_ws, size_t ws_size,
                              hipStream_t stream)
{
    (void)in_sizes; (void)n_in; (void)out_size; (void)ws_size;
    const float* x     = (const float*)d_in[0];
    const float* t     = (const float*)d_in[1];
    const float* L     = (const float*)d_in[2];
    const float* w_g1  = (const float*)d_in[3];
    const float* w_g2  = (const float*)d_in[4];
    const float* w_t1  = (const float*)d_in[5];
    const float* b_t1  = (const float*)d_in[6];
    const float* w_t2  = (const float*)d_in[7];
    const float* b_t2  = (const float*)d_in[8];
    const float* w_map = (const float*)d_in[9];
    const float* b_map = (const float*)d_in[10];
    const float* res_w = (const float*)d_in[11];
    const float* res_b = (const float*)d_in[12];
    const float* w_o1  = (const float*)d_in[13];
    const float* b_o1  = (const float*)d_in[14];
    const float* w_o2  = (const float*)d_in[15];
    const float* b_o2  = (const float*)d_in[16];
    float* out = (float*)d_out;
    char* ws = (char*)d_ws;

    float* a_c  = (float*)(ws + WS_A);
    float* tout = (float*)(ws + WS_TOUT);
    float* z1   = (float*)(ws + WS_Z1);
    float* z2   = (float*)(ws + WS_Z1 + WS_ZSTR);
    float* z3   = (float*)(ws + WS_Z1 + 2 * WS_ZSTR);
    float* z4   = (float*)(ws + WS_Z1 + 3 * WS_ZSTR);
    float* h0   = (float*)(ws + WS_H0);
    float* g2   = (float*)(ws + WS_G2F);
    __bf16* u_b    = (__bf16*)(ws + WS_UB);
    __bf16* w_mapT = (__bf16*)(ws + WS_WMAPT);
    __bf16* w_o2T  = (__bf16*)(ws + WS_WO2T);
    __bf16* Lb     = (__bf16*)(ws + WS_LBF);

    prep_kernel<<<PG_TOTAL, 256, 0, stream>>>(t, L, w_g1, w_g2, w_t1, b_t1, w_t2, b_t2,
                                              w_map, w_o2, ws);
    hop_kernel<<<1024, 256, 0, stream>>>(Lb, x,  z1);
    hop_kernel<<<1024, 256, 0, stream>>>(Lb, z1, z2);
    hop_kernel<<<1024, 256, 0, stream>>>(Lb, z2, z3);
    hop_kernel<<<1024, 256, 0, stream>>>(Lb, z3, z4);
    combine_kernel<<<128, 256, 0, stream>>>(x, z1, z2, z3, z4, a_c, g2);
    map_gemm_kernel<<<128, 256, 0, stream>>>(g2, w_mapT, h0);
    resnet_kernel<<<32, 1024, 0, stream>>>(h0, b_map, res_w, res_b, tout, w_o1, b_o1, u_b);
    out_gemm_kernel<<<64, 256, 0, stream>>>(u_b, w_o2T, b_o2, out);
}

// Round 6
// 283.369 us; speedup vs baseline: 1.6156x; 1.6156x over previous
//
#include <hip/hip_runtime.h>
#include <hip/hip_bf16.h>

typedef __bf16 bf16x8 __attribute__((ext_vector_type(8)));
typedef __bf16 bf16x4 __attribute__((ext_vector_type(4)));
typedef float  f32x4  __attribute__((ext_vector_type(4)));

// Problem constants: B=32, N=4096, H=256, TDIM=128, K=2, R=2

// ---- workspace byte offsets ----
static constexpr size_t WS_A     = 0;                   // 5 f32 combine coeffs
static constexpr size_t WS_TOUT  = 1024;                // t_out [32,256] f32
static constexpr size_t WS_Z1    = 65536;               // z1..z3 [32,4096] f32 each
static constexpr size_t WS_ZSTR  = 524288;
static constexpr size_t WS_H0    = WS_Z1 + 4 * WS_ZSTR; // h0 [32,256] f32
static constexpr size_t WS_G2F   = WS_H0 + 32768;       // g2 [32,4096] f32
static constexpr size_t WS_UB    = WS_G2F + 524288;     // u [32,256] bf16
static constexpr size_t WS_WMAPT = 2752512;             // w_map^T [256,4096] bf16
static constexpr size_t WS_WO2T  = WS_WMAPT + 2097152;  // w_o2^T [4096,256] bf16
static constexpr size_t WS_LBF   = 8388608;             // L bf16 [4096,4096] (32 MB)

__device__ __forceinline__ f32x4 mfma16(bf16x8 a, bf16x8 b, f32x4 c) {
    return __builtin_amdgcn_mfma_f32_16x16x32_bf16(a, b, c, 0, 0, 0);
}

__device__ __forceinline__ bf16x8 pack8(f32x4 lo, f32x4 hi) {
    bf16x8 r;
    r[0] = (__bf16)lo[0]; r[1] = (__bf16)lo[1]; r[2] = (__bf16)lo[2]; r[3] = (__bf16)lo[3];
    r[4] = (__bf16)hi[0]; r[5] = (__bf16)hi[1]; r[6] = (__bf16)hi[2]; r[7] = (__bf16)hi[3];
    return r;
}

__device__ __forceinline__ bf16x8 cvt8(const float* p) {
    return pack8(*(const f32x4*)p, *(const f32x4*)(p + 4));
}

__device__ __forceinline__ float silu_f(float x) { return x / (1.0f + __expf(-x)); }

// y[col] = sum_j zs[j] * W[j*256+col], K = NST*16, double-buffered prefetch.
template <int NST>
__device__ __forceinline__ float dotW(const float* __restrict__ W,
                                      const float* __restrict__ zs, int col) {
    float wb[2][16];
#pragma unroll
    for (int u = 0; u < 16; ++u) wb[0][u] = W[u * 256 + col];
    float a0 = 0, a1 = 0, a2 = 0, a3 = 0;
#pragma unroll
    for (int g = 0; g < NST; ++g) {
        const int cur = g & 1, nxt = cur ^ 1;
        if (g < NST - 1) {
#pragma unroll
            for (int u = 0; u < 16; ++u) wb[nxt][u] = W[((g + 1) * 16 + u) * 256 + col];
        }
        const float* z = zs + g * 16;
#pragma unroll
        for (int u = 0; u < 16; u += 4) {
            a0 += z[u]     * wb[cur][u];
            a1 += z[u + 1] * wb[cur][u + 1];
            a2 += z[u + 2] * wb[cur][u + 2];
            a3 += z[u + 3] * wb[cur][u + 3];
        }
    }
    return (a0 + a1) + (a2 + a3);
}

// 32x32 tile transpose f32 -> bf16 via LDS
__device__ __forceinline__ void transpose_tile(const float* __restrict__ src, int sstride,
                                               __bf16* __restrict__ dst, int dstride,
                                               int r0, int c0, float* sh, int tid) {
    const int r = tid >> 3, cg = (tid & 7) * 4;
    f32x4 v = *(const f32x4*)(src + (size_t)(r0 + r) * sstride + c0 + cg);
    sh[r * 33 + cg + 0] = v[0];
    sh[r * 33 + cg + 1] = v[1];
    sh[r * 33 + cg + 2] = v[2];
    sh[r * 33 + cg + 3] = v[3];
    __syncthreads();
    bf16x4 o;
    o[0] = (__bf16)sh[(cg + 0) * 33 + r];
    o[1] = (__bf16)sh[(cg + 1) * 33 + r];
    o[2] = (__bf16)sh[(cg + 2) * 33 + r];
    o[3] = (__bf16)sh[(cg + 3) * 33 + r];
    *(bf16x4*)(dst + (size_t)(c0 + r) * dstride + r0 + cg) = o;
}

// prep grid ranges (no zero-init needed anymore: all buffers fully written)
static constexpr int PG_LCVT  = 8192;              // L f32 -> bf16
static constexpr int PG_COEF  = PG_LCVT;           // 8192
static constexpr int PG_TMLP  = PG_COEF + 1;       // 8193..8224
static constexpr int PG_WMAP  = PG_TMLP + 32;      // 8225..9248
static constexpr int PG_WO2   = PG_WMAP + 1024;    // 9249..10272
static constexpr int PG_TOTAL = PG_WO2 + 1024;     // 10273

__global__ __launch_bounds__(256) void prep_kernel(
    const float* __restrict__ t, const float* __restrict__ L,
    const float* __restrict__ w_g1, const float* __restrict__ w_g2,
    const float* __restrict__ w_t1, const float* __restrict__ b_t1,
    const float* __restrict__ w_t2, const float* __restrict__ b_t2,
    const float* __restrict__ w_map, const float* __restrict__ w_o2,
    char* __restrict__ ws)
{
    __shared__ float sh[1056];
    const int bi = blockIdx.x, tid = threadIdx.x;
    if (bi < PG_LCVT) {
        const size_t base = (size_t)bi * 2048 + (size_t)tid * 8;
        *(bf16x8*)((__bf16*)(ws + WS_LBF) + base) = cvt8(L + base);
    } else if (bi == PG_COEF) {
        if (tid < 9) {
            const int k1 = tid / 3, k2 = tid % 3;
            float s = 0.f;
            for (int h = 0; h < 256; ++h) s += w_g1[h * 3 + k1] * w_g2[h * 3 + k2];
            sh[tid] = s;
        }
        __syncthreads();
        if (tid == 0) {
            float* a = (float*)(ws + WS_A);
            a[0] = sh[0];
            a[1] = sh[1] + sh[3];
            a[2] = sh[2] + sh[4] + sh[6];
            a[3] = sh[5] + sh[7];
            a[4] = sh[8];
        }
    } else if (bi < PG_WMAP) {
        const int b = bi - PG_TMLP;
        float* t_out = (float*)(ws + WS_TOUT);
        if (tid < 64) {
            float fr = __expf(-9.210340371976184f * (float)tid * (1.0f / 64.0f));
            float ang = t[b] * fr;
            sh[tid]      = __cosf(ang);
            sh[64 + tid] = __sinf(ang);
        }
        __syncthreads();
        float h1 = silu_f(b_t1[tid] + dotW<8>(w_t1, sh, tid));
        sh[128 + tid] = h1;
        __syncthreads();
        t_out[b * 256 + tid] = b_t2[tid] + dotW<16>(w_t2, sh + 128, tid);
    } else if (bi < PG_WO2) {
        const int ti = bi - PG_WMAP;
        transpose_tile(w_map, 256, (__bf16*)(ws + WS_WMAPT), 4096,
                       (ti >> 3) * 32, (ti & 7) * 32, sh, tid);
    } else {
        const int ti = bi - PG_WO2;
        transpose_tile(w_o2, 4096, (__bf16*)(ws + WS_WO2T), 256,
                       (ti & 7) * 32, (ti >> 3) * 32, sh, tid);
    }
}

// Hop body: per block m-tile 16 (m0 = bi*16), full K=4096 split over 4 waves
// (wave k-range 1024 = 32 steps). Depth-4 circular register prefetch; LDS
// cross-wave reduce; NO atomics. Result in v for (m = o&15, bc = o>>4),
// o = tid and tid+256.
__device__ __forceinline__ void hop_core(
    const __bf16* __restrict__ Lb, const float* __restrict__ zin,
    float (*red)[16][33], int bi, int tid, float v[2])
{
    const int wave = tid >> 6, lane = tid & 63;
    const int l15 = lane & 15, q = lane >> 4;
    const int m0 = bi * 16;
    const int kbase = wave * 1024 + q * 8;

    const __bf16* ap  = Lb + (size_t)(m0 + l15) * 4096 + kbase;
    const float*  b0p = zin + (size_t)l15 * 4096 + kbase;
    const float*  b1p = zin + (size_t)(l15 + 16) * 4096 + kbase;

    bf16x8 abuf[4];
    f32x4 b0lo[4], b0hi[4], b1lo[4], b1hi[4];
    f32x4 acc0 = {0,0,0,0}, acc1 = {0,0,0,0};
#pragma unroll
    for (int s = 0; s < 3; ++s) {
        const int k = s * 32;
        abuf[s] = *(const bf16x8*)(ap + k);
        b0lo[s] = *(const f32x4*)(b0p + k);
        b0hi[s] = *(const f32x4*)(b0p + k + 4);
        b1lo[s] = *(const f32x4*)(b1p + k);
        b1hi[s] = *(const f32x4*)(b1p + k + 4);
    }
#pragma unroll
    for (int s = 0; s < 32; ++s) {
        const int cur = s & 3;
        if (s < 29) {
            const int kn = (s + 3) * 32;
            const int nxt = (s + 3) & 3;
            abuf[nxt] = *(const bf16x8*)(ap + kn);
            b0lo[nxt] = *(const f32x4*)(b0p + kn);
            b0hi[nxt] = *(const f32x4*)(b0p + kn + 4);
            b1lo[nxt] = *(const f32x4*)(b1p + kn);
            b1hi[nxt] = *(const f32x4*)(b1p + kn + 4);
        }
        bf16x8 b0 = pack8(b0lo[cur], b0hi[cur]);
        bf16x8 b1 = pack8(b1lo[cur], b1hi[cur]);
        acc0 = mfma16(abuf[cur], b0, acc0);
        acc1 = mfma16(abuf[cur], b1, acc1);
    }
    // C layout: col = lane&15 (b-dim), row = q*4+reg (m-dim)
#pragma unroll
    for (int r = 0; r < 4; ++r) {
        const int mr = q * 4 + r;
        red[wave][mr][l15]      = acc0[r];
        red[wave][mr][l15 + 16] = acc1[r];
    }
    __syncthreads();
#pragma unroll
    for (int j = 0; j < 2; ++j) {
        const int o = tid + 256 * j;
        const int m = o & 15, bc = o >> 4;
        v[j] = red[0][m][bc] + red[1][m][bc] + red[2][m][bc] + red[3][m][bc];
    }
}

// Hops 1-3: zout = L @ zin, plain stores.
__global__ __launch_bounds__(256) void hop_kernel(
    const __bf16* __restrict__ Lb, const float* __restrict__ zin,
    float* __restrict__ zout)
{
    __shared__ float red[4][16][33];
    const int bi = blockIdx.x, tid = threadIdx.x;
    float v[2];
    hop_core(Lb, zin, red, bi, tid, v);
    const int m0 = bi * 16;
#pragma unroll
    for (int j = 0; j < 2; ++j) {
        const int o = tid + 256 * j;
        const int m = o & 15, bc = o >> 4;
        zout[(size_t)bc * 4096 + m0 + m] = v[j];
    }
}

// Hop 4 fused with combine: g2 = a0*x + a1*z1 + a2*z2 + a3*z3 + a4*(L@z3).
__global__ __launch_bounds__(256) void hop_final_kernel(
    const __bf16* __restrict__ Lb, const float* __restrict__ z3,
    const float* __restrict__ x, const float* __restrict__ z1,
    const float* __restrict__ z2, const float* __restrict__ a,
    float* __restrict__ g2)
{
    __shared__ float red[4][16][33];
    const int bi = blockIdx.x, tid = threadIdx.x;
    float v[2];
    hop_core(Lb, z3, red, bi, tid, v);
    const int m0 = bi * 16;
    const float c0 = a[0], c1 = a[1], c2 = a[2], c3 = a[3], c4 = a[4];
#pragma unroll
    for (int j = 0; j < 2; ++j) {
        const int o = tid + 256 * j;
        const int m = o & 15, bc = o >> 4;
        const size_t idx = (size_t)bc * 4096 + m0 + m;
        g2[idx] = c0 * x[idx] + c1 * z1[idx] + c2 * z2[idx] + c3 * z3[idx] + c4 * v[j];
    }
}

// h0 = g2 @ w_map: grid 16 (btile x hp), 512 thr = 8 waves x 512-K, plain stores.
__global__ __launch_bounds__(512) void map_gemm_kernel(
    const float* __restrict__ g2, const __bf16* __restrict__ w_mapT,
    float* __restrict__ h0)
{
    __shared__ float red[8][16][33];
    const int bi = blockIdx.x, tid = threadIdx.x;
    const int wave = tid >> 6, lane = tid & 63;
    const int l15 = lane & 15, q = lane >> 4;
    const int btile = bi & 1, hp = bi >> 1;
    const int kbase = wave * 512 + q * 8;

    const float*  ap  = g2 + (size_t)(btile * 16 + l15) * 4096 + kbase;
    const __bf16* bp0 = w_mapT + (size_t)(hp * 32 + l15) * 4096 + kbase;
    const __bf16* bp1 = w_mapT + (size_t)(hp * 32 + 16 + l15) * 4096 + kbase;

    f32x4 alo[4], ahi[4];
    bf16x8 b0b[4], b1b[4];
    f32x4 acc0 = {0,0,0,0}, acc1 = {0,0,0,0};
#pragma unroll
    for (int s = 0; s < 3; ++s) {
        const int k = s * 32;
        alo[s] = *(const f32x4*)(ap + k);
        ahi[s] = *(const f32x4*)(ap + k + 4);
        b0b[s] = *(const bf16x8*)(bp0 + k);
        b1b[s] = *(const bf16x8*)(bp1 + k);
    }
#pragma unroll
    for (int s = 0; s < 16; ++s) {
        const int cur = s & 3;
        if (s < 13) {
            const int kn = (s + 3) * 32;
            const int nxt = (s + 3) & 3;
            alo[nxt] = *(const f32x4*)(ap + kn);
            ahi[nxt] = *(const f32x4*)(ap + kn + 4);
            b0b[nxt] = *(const bf16x8*)(bp0 + kn);
            b1b[nxt] = *(const bf16x8*)(bp1 + kn);
        }
        bf16x8 av = pack8(alo[cur], ahi[cur]);
        acc0 = mfma16(av, b0b[cur], acc0);
        acc1 = mfma16(av, b1b[cur], acc1);
    }
#pragma unroll
    for (int r = 0; r < 4; ++r) {
        const int mr = q * 4 + r;
        red[wave][mr][l15]      = acc0[r];
        red[wave][mr][l15 + 16] = acc1[r];
    }
    __syncthreads();
    // 512 outputs: m = tid>>5 (batch within tile), hcol = tid&31
    const int m = tid >> 5, hcol = tid & 31;
    float v = 0.f;
#pragma unroll
    for (int w = 0; w < 8; ++w) v += red[w][m][hcol];
    h0[(size_t)(btile * 16 + m) * 256 + hp * 32 + hcol] = v;
}

// ResNet_FC + head to u (bf16). 1024 thr: col=tid&255, kg=tid>>8.
__global__ __launch_bounds__(1024) void resnet_kernel(
    const float* __restrict__ h0, const float* __restrict__ b_map,
    const float* __restrict__ res_w, const float* __restrict__ res_b,
    const float* __restrict__ t_out, const float* __restrict__ w_o1,
    const float* __restrict__ b_o1, __bf16* __restrict__ u_b)
{
    __shared__ float zs[256];
    __shared__ float part[4][256];
    const int b = blockIdx.x, tid = threadIdx.x;
    const int col = tid & 255, kg = tid >> 8;

    float hv = 0.f;
    if (kg == 0) {
        hv = h0[b * 256 + col] + b_map[col];
        zs[col] = hv;
    }
    __syncthreads();

#pragma unroll
    for (int r = 0; r < 2; ++r) {
        for (int i = 0; i < 3; ++i) {
            part[kg][col] = dotW<4>(res_w + ((size_t)(r * 3 + i) << 16) + (size_t)kg * 64 * 256,
                                    zs + kg * 64, col);
            __syncthreads();
            if (kg == 0) {
                zs[col] = silu_f(res_b[(r * 3 + i) * 256 + col]
                                 + part[0][col] + part[1][col] + part[2][col] + part[3][col]);
            }
            __syncthreads();
        }
        if (kg == 0) {
            hv = (hv + zs[col]) * 0.70710678118654752f;
            zs[col] = hv;
        }
        __syncthreads();
    }

    if (kg == 0) zs[col] = hv + t_out[b * 256 + col];
    __syncthreads();
    part[kg][col] = dotW<4>(w_o1 + (size_t)kg * 64 * 256, zs + kg * 64, col);
    __syncthreads();
    if (kg == 0) {
        u_b[b * 256 + col] = (__bf16)silu_f(b_o1[col]
            + part[0][col] + part[1][col] + part[2][col] + part[3][col]);
    }
}

// out[b,n] = sum_h u[b,h] * w_o2[h,n] + b_o2[n]   (K=256, full-K per wave)
__global__ __launch_bounds__(256) void out_gemm_kernel(
    const __bf16* __restrict__ u_b, const __bf16* __restrict__ w_o2T,
    const float* __restrict__ b_o2, float* __restrict__ out)
{
    const int tid = threadIdx.x;
    const int wave = tid >> 6, lane = tid & 63;
    const int l15 = lane & 15, q = lane >> 4;
    const int g = blockIdx.x * 4 + wave;
    const int btile = g & 1;
    const int n0 = (g >> 1) * 32;

    const __bf16* ap  = u_b + (size_t)(btile * 16 + l15) * 256;
    const __bf16* bp0 = w_o2T + (size_t)(n0 + l15) * 256;
    const __bf16* bp1 = w_o2T + (size_t)(n0 + 16 + l15) * 256;

    f32x4 acc0 = {0,0,0,0}, acc1 = {0,0,0,0};
#pragma unroll
    for (int ks = 0; ks < 8; ++ks) {
        const int k = ks * 32 + q * 8;
        bf16x8 a  = *(const bf16x8*)(ap + k);
        bf16x8 b0 = *(const bf16x8*)(bp0 + k);
        bf16x8 b1 = *(const bf16x8*)(bp1 + k);
        acc0 = mfma16(a, b0, acc0);
        acc1 = mfma16(a, b1, acc1);
    }
    const int row = btile * 16 + q * 4;
    const int na = n0 + l15, nb = n0 + 16 + l15;
#pragma unroll
    for (int r = 0; r < 4; ++r) {
        out[(size_t)(row + r) * 4096 + na] = acc0[r] + b_o2[na];
        out[(size_t)(row + r) * 4096 + nb] = acc1[r] + b_o2[nb];
    }
}

extern "C" void kernel_launch(void* const* d_in, const int* in_sizes, int n_in,
                              void* d_out, int out_size, void* d_ws, size_t ws_size,
                              hipStream_t stream)
{
    (void)in_sizes; (void)n_in; (void)out_size; (void)ws_size;
    const float* x     = (const float*)d_in[0];
    const float* t     = (const float*)d_in[1];
    const float* L     = (const float*)d_in[2];
    const float* w_g1  = (const float*)d_in[3];
    const float* w_g2  = (const float*)d_in[4];
    const float* w_t1  = (const float*)d_in[5];
    const float* b_t1  = (const float*)d_in[6];
    const float* w_t2  = (const float*)d_in[7];
    const float* b_t2  = (const float*)d_in[8];
    const float* w_map = (const float*)d_in[9];
    const float* b_map = (const float*)d_in[10];
    const float* res_w = (const float*)d_in[11];
    const float* res_b = (const float*)d_in[12];
    const float* w_o1  = (const float*)d_in[13];
    const float* b_o1  = (const float*)d_in[14];
    const float* w_o2  = (const float*)d_in[15];
    const float* b_o2  = (const float*)d_in[16];
    float* out = (float*)d_out;
    char* ws = (char*)d_ws;

    float* a_c  = (float*)(ws + WS_A);
    float* tout = (float*)(ws + WS_TOUT);
    float* z1   = (float*)(ws + WS_Z1);
    float* z2   = (float*)(ws + WS_Z1 + WS_ZSTR);
    float* z3   = (float*)(ws + WS_Z1 + 2 * WS_ZSTR);
    float* h0   = (float*)(ws + WS_H0);
    float* g2   = (float*)(ws + WS_G2F);
    __bf16* u_b    = (__bf16*)(ws + WS_UB);
    __bf16* w_mapT = (__bf16*)(ws + WS_WMAPT);
    __bf16* w_o2T  = (__bf16*)(ws + WS_WO2T);
    __bf16* Lb     = (__bf16*)(ws + WS_LBF);

    prep_kernel<<<PG_TOTAL, 256, 0, stream>>>(t, L, w_g1, w_g2, w_t1, b_t1, w_t2, b_t2,
                                              w_map, w_o2, ws);
    hop_kernel<<<256, 256, 0, stream>>>(Lb, x,  z1);
    hop_kernel<<<256, 256, 0, stream>>>(Lb, z1, z2);
    hop_kernel<<<256, 256, 0, stream>>>(Lb, z2, z3);
    hop_final_kernel<<<256, 256, 0, stream>>>(Lb, z3, x, z1, z2, a_c, g2);
    map_gemm_kernel<<<16, 512, 0, stream>>>(g2, w_mapT, h0);
    resnet_kernel<<<32, 1024, 0, stream>>>(h0, b_map, res_w, res_b, tout, w_o1, b_o1, u_b);
    out_gemm_kernel<<<64, 256, 0, stream>>>(u_b, w_o2T, b_o2, out);
}

// Round 7
// 252.994 us; speedup vs baseline: 1.8096x; 1.1201x over previous
//
#include <hip/hip_runtime.h>
#include <hip/hip_bf16.h>

typedef __bf16 bf16x8 __attribute__((ext_vector_type(8)));
typedef __bf16 bf16x4 __attribute__((ext_vector_type(4)));
typedef float  f32x4  __attribute__((ext_vector_type(4)));

// Problem constants: B=32, N=4096, H=256, TDIM=128, K=2, R=2

// ---- workspace byte offsets ----
static constexpr size_t WS_A     = 0;                    // 5 f32 combine coeffs
static constexpr size_t WS_TOUT  = 1024;                 // t_out [32,256] f32
static constexpr size_t WS_ZB    = 65536;                // z1..z3 bf16 [32,4096] each
static constexpr size_t WS_ZSTR  = 262144;
static constexpr size_t WS_G2B   = WS_ZB + 3 * WS_ZSTR;  // g2 bf16 [32,4096]
static constexpr size_t WS_H0    = WS_G2B + 262144;      // h0 [32,256] f32
static constexpr size_t WS_UB    = WS_H0 + 32768;        // u [32,256] bf16
static constexpr size_t WS_WMAPT = 1179648;              // w_map^T [256,4096] bf16 (2MB)
static constexpr size_t WS_WO2T  = WS_WMAPT + 2097152;   // w_o2^T [4096,256] bf16 (2MB)
static constexpr size_t WS_LBF   = 8388608;              // L bf16 [4096,4096] (32 MB)

__device__ __forceinline__ f32x4 mfma16(bf16x8 a, bf16x8 b, f32x4 c) {
    return __builtin_amdgcn_mfma_f32_16x16x32_bf16(a, b, c, 0, 0, 0);
}

__device__ __forceinline__ bf16x8 pack8(f32x4 lo, f32x4 hi) {
    bf16x8 r;
    r[0] = (__bf16)lo[0]; r[1] = (__bf16)lo[1]; r[2] = (__bf16)lo[2]; r[3] = (__bf16)lo[3];
    r[4] = (__bf16)hi[0]; r[5] = (__bf16)hi[1]; r[6] = (__bf16)hi[2]; r[7] = (__bf16)hi[3];
    return r;
}

__device__ __forceinline__ float silu_f(float x) { return x / (1.0f + __expf(-x)); }

// y[col] = sum_j zs[j] * W[j*256+col], K = NST*16, double-buffered prefetch.
template <int NST>
__device__ __forceinline__ float dotW(const float* __restrict__ W,
                                      const float* __restrict__ zs, int col) {
    float wb[2][16];
#pragma unroll
    for (int u = 0; u < 16; ++u) wb[0][u] = W[u * 256 + col];
    float a0 = 0, a1 = 0, a2 = 0, a3 = 0;
#pragma unroll
    for (int g = 0; g < NST; ++g) {
        const int cur = g & 1, nxt = cur ^ 1;
        if (g < NST - 1) {
#pragma unroll
            for (int u = 0; u < 16; ++u) wb[nxt][u] = W[((g + 1) * 16 + u) * 256 + col];
        }
        const float* z = zs + g * 16;
#pragma unroll
        for (int u = 0; u < 16; u += 4) {
            a0 += z[u]     * wb[cur][u];
            a1 += z[u + 1] * wb[cur][u + 1];
            a2 += z[u + 2] * wb[cur][u + 2];
            a3 += z[u + 3] * wb[cur][u + 3];
        }
    }
    return (a0 + a1) + (a2 + a3);
}

// 32x32 tile transpose f32 -> bf16 via LDS
__device__ __forceinline__ void transpose_tile(const float* __restrict__ src, int sstride,
                                               __bf16* __restrict__ dst, int dstride,
                                               int r0, int c0, float* sh, int tid) {
    const int r = tid >> 3, cg = (tid & 7) * 4;
    f32x4 v = *(const f32x4*)(src + (size_t)(r0 + r) * sstride + c0 + cg);
    sh[r * 33 + cg + 0] = v[0];
    sh[r * 33 + cg + 1] = v[1];
    sh[r * 33 + cg + 2] = v[2];
    sh[r * 33 + cg + 3] = v[3];
    __syncthreads();
    bf16x4 o;
    o[0] = (__bf16)sh[(cg + 0) * 33 + r];
    o[1] = (__bf16)sh[(cg + 1) * 33 + r];
    o[2] = (__bf16)sh[(cg + 2) * 33 + r];
    o[3] = (__bf16)sh[(cg + 3) * 33 + r];
    *(bf16x4*)(dst + (size_t)(c0 + r) * dstride + r0 + cg) = o;
}

// prep: coeffs (1), tMLP (32), w_map transpose (1024), w_o2 transpose (1024)
__global__ __launch_bounds__(256) void prep_kernel(
    const float* __restrict__ t,
    const float* __restrict__ w_g1, const float* __restrict__ w_g2,
    const float* __restrict__ w_t1, const float* __restrict__ b_t1,
    const float* __restrict__ w_t2, const float* __restrict__ b_t2,
    const float* __restrict__ w_map, const float* __restrict__ w_o2,
    char* __restrict__ ws)
{
    __shared__ float sh[1056];
    const int bi = blockIdx.x, tid = threadIdx.x;
    if (bi == 0) {
        if (tid < 9) {
            const int k1 = tid / 3, k2 = tid % 3;
            float s = 0.f;
            for (int h = 0; h < 256; ++h) s += w_g1[h * 3 + k1] * w_g2[h * 3 + k2];
            sh[tid] = s;
        }
        __syncthreads();
        if (tid == 0) {
            float* a = (float*)(ws + WS_A);
            a[0] = sh[0];
            a[1] = sh[1] + sh[3];
            a[2] = sh[2] + sh[4] + sh[6];
            a[3] = sh[5] + sh[7];
            a[4] = sh[8];
        }
    } else if (bi < 33) {
        const int b = bi - 1;
        float* t_out = (float*)(ws + WS_TOUT);
        if (tid < 64) {
            float fr = __expf(-9.210340371976184f * (float)tid * (1.0f / 64.0f));
            float ang = t[b] * fr;
            sh[tid]      = __cosf(ang);
            sh[64 + tid] = __sinf(ang);
        }
        __syncthreads();
        float h1 = silu_f(b_t1[tid] + dotW<8>(w_t1, sh, tid));
        sh[128 + tid] = h1;
        __syncthreads();
        t_out[b * 256 + tid] = b_t2[tid] + dotW<16>(w_t2, sh + 128, tid);
    } else if (bi < 1057) {
        const int ti = bi - 33;
        transpose_tile(w_map, 256, (__bf16*)(ws + WS_WMAPT), 4096,
                       (ti >> 3) * 32, (ti & 7) * 32, sh, tid);
    } else {
        const int ti = bi - 1057;
        transpose_tile(w_o2, 4096, (__bf16*)(ws + WS_WO2T), 256,
                       (ti & 7) * 32, (ti >> 3) * 32, sh, tid);
    }
}

// Hop 1 fused with L convert: reads L f32 (HBM), converts in-register, writes
// Lb bf16 (for hops 2-4), computes z1 = L @ x, stores z1 bf16.
// Grid 256 x 512 thr: m-tile 16, 8 waves x K=512 (16 steps), depth-3 prefetch.
__global__ __launch_bounds__(512) void hop1_kernel(
    const float* __restrict__ L, const float* __restrict__ x,
    __bf16* __restrict__ Lb, __bf16* __restrict__ z1b)
{
    __shared__ float red[8][16][33];
    const int bi = blockIdx.x, tid = threadIdx.x;
    const int wave = tid >> 6, lane = tid & 63;
    const int l15 = lane & 15, q = lane >> 4;
    const int m0 = bi * 16;
    const int kbase = wave * 512 + q * 8;

    const float* ap  = L + (size_t)(m0 + l15) * 4096 + kbase;
    __bf16*      lbp = Lb + (size_t)(m0 + l15) * 4096 + kbase;
    const float* b0p = x + (size_t)l15 * 4096 + kbase;
    const float* b1p = x + (size_t)(l15 + 16) * 4096 + kbase;

    f32x4 alo[3], ahi[3], b0lo[3], b0hi[3], b1lo[3], b1hi[3];
    f32x4 acc0 = {0,0,0,0}, acc1 = {0,0,0,0};
#pragma unroll
    for (int s = 0; s < 2; ++s) {
        const int k = s * 32;
        alo[s]  = *(const f32x4*)(ap + k);   ahi[s]  = *(const f32x4*)(ap + k + 4);
        b0lo[s] = *(const f32x4*)(b0p + k);  b0hi[s] = *(const f32x4*)(b0p + k + 4);
        b1lo[s] = *(const f32x4*)(b1p + k);  b1hi[s] = *(const f32x4*)(b1p + k + 4);
    }
#pragma unroll
    for (int s = 0; s < 16; ++s) {
        const int cur = s % 3;
        if (s < 14) {
            const int nxt = (s + 2) % 3;
            const int kn = (s + 2) * 32;
            alo[nxt]  = *(const f32x4*)(ap + kn);   ahi[nxt]  = *(const f32x4*)(ap + kn + 4);
            b0lo[nxt] = *(const f32x4*)(b0p + kn);  b0hi[nxt] = *(const f32x4*)(b0p + kn + 4);
            b1lo[nxt] = *(const f32x4*)(b1p + kn);  b1hi[nxt] = *(const f32x4*)(b1p + kn + 4);
        }
        bf16x8 av = pack8(alo[cur], ahi[cur]);
        *(bf16x8*)(lbp + s * 32) = av;
        bf16x8 b0 = pack8(b0lo[cur], b0hi[cur]);
        bf16x8 b1 = pack8(b1lo[cur], b1hi[cur]);
        acc0 = mfma16(av, b0, acc0);
        acc1 = mfma16(av, b1, acc1);
    }
#pragma unroll
    for (int r = 0; r < 4; ++r) {
        const int mr = q * 4 + r;
        red[wave][mr][l15]      = acc0[r];
        red[wave][mr][l15 + 16] = acc1[r];
    }
    __syncthreads();
    const int m = tid & 15, bc = tid >> 4;
    float v = 0.f;
#pragma unroll
    for (int w = 0; w < 8; ++w) v += red[w][m][bc];
    z1b[(size_t)bc * 4096 + m0 + m] = (__bf16)v;
}

// Hops 2-3: all-bf16. zout = L @ zin. Depth-4 prefetch, 3x bf16x8 loads/step.
__global__ __launch_bounds__(512) void hop_kernel(
    const __bf16* __restrict__ Lb, const __bf16* __restrict__ zin,
    __bf16* __restrict__ zout)
{
    __shared__ float red[8][16][33];
    const int bi = blockIdx.x, tid = threadIdx.x;
    const int wave = tid >> 6, lane = tid & 63;
    const int l15 = lane & 15, q = lane >> 4;
    const int m0 = bi * 16;
    const int kbase = wave * 512 + q * 8;

    const __bf16* ap  = Lb + (size_t)(m0 + l15) * 4096 + kbase;
    const __bf16* b0p = zin + (size_t)l15 * 4096 + kbase;
    const __bf16* b1p = zin + (size_t)(l15 + 16) * 4096 + kbase;

    bf16x8 ab[4], b0b[4], b1b[4];
    f32x4 acc0 = {0,0,0,0}, acc1 = {0,0,0,0};
#pragma unroll
    for (int s = 0; s < 3; ++s) {
        const int k = s * 32;
        ab[s]  = *(const bf16x8*)(ap + k);
        b0b[s] = *(const bf16x8*)(b0p + k);
        b1b[s] = *(const bf16x8*)(b1p + k);
    }
#pragma unroll
    for (int s = 0; s < 16; ++s) {
        const int cur = s & 3;
        if (s < 13) {
            const int nxt = (s + 3) & 3;
            const int kn = (s + 3) * 32;
            ab[nxt]  = *(const bf16x8*)(ap + kn);
            b0b[nxt] = *(const bf16x8*)(b0p + kn);
            b1b[nxt] = *(const bf16x8*)(b1p + kn);
        }
        acc0 = mfma16(ab[cur], b0b[cur], acc0);
        acc1 = mfma16(ab[cur], b1b[cur], acc1);
    }
#pragma unroll
    for (int r = 0; r < 4; ++r) {
        const int mr = q * 4 + r;
        red[wave][mr][l15]      = acc0[r];
        red[wave][mr][l15 + 16] = acc1[r];
    }
    __syncthreads();
    const int m = tid & 15, bc = tid >> 4;
    float v = 0.f;
#pragma unroll
    for (int w = 0; w < 8; ++w) v += red[w][m][bc];
    zout[(size_t)bc * 4096 + m0 + m] = (__bf16)v;
}

// Hop 4 fused with combine: g2 = a0*x + a1*z1 + a2*z2 + a3*z3 + a4*(L@z3), bf16 out.
__global__ __launch_bounds__(512) void hop_final_kernel(
    const __bf16* __restrict__ Lb, const __bf16* __restrict__ z3b,
    const float* __restrict__ x, const __bf16* __restrict__ z1b,
    const __bf16* __restrict__ z2b, const float* __restrict__ a,
    __bf16* __restrict__ g2b)
{
    __shared__ float red[8][16][33];
    const int bi = blockIdx.x, tid = threadIdx.x;
    const int wave = tid >> 6, lane = tid & 63;
    const int l15 = lane & 15, q = lane >> 4;
    const int m0 = bi * 16;
    const int kbase = wave * 512 + q * 8;

    const __bf16* ap  = Lb + (size_t)(m0 + l15) * 4096 + kbase;
    const __bf16* b0p = z3b + (size_t)l15 * 4096 + kbase;
    const __bf16* b1p = z3b + (size_t)(l15 + 16) * 4096 + kbase;

    bf16x8 ab[4], b0b[4], b1b[4];
    f32x4 acc0 = {0,0,0,0}, acc1 = {0,0,0,0};
#pragma unroll
    for (int s = 0; s < 3; ++s) {
        const int k = s * 32;
        ab[s]  = *(const bf16x8*)(ap + k);
        b0b[s] = *(const bf16x8*)(b0p + k);
        b1b[s] = *(const bf16x8*)(b1p + k);
    }
#pragma unroll
    for (int s = 0; s < 16; ++s) {
        const int cur = s & 3;
        if (s < 13) {
            const int nxt = (s + 3) & 3;
            const int kn = (s + 3) * 32;
            ab[nxt]  = *(const bf16x8*)(ap + kn);
            b0b[nxt] = *(const bf16x8*)(b0p + kn);
            b1b[nxt] = *(const bf16x8*)(b1p + kn);
        }
        acc0 = mfma16(ab[cur], b0b[cur], acc0);
        acc1 = mfma16(ab[cur], b1b[cur], acc1);
    }
#pragma unroll
    for (int r = 0; r < 4; ++r) {
        const int mr = q * 4 + r;
        red[wave][mr][l15]      = acc0[r];
        red[wave][mr][l15 + 16] = acc1[r];
    }
    __syncthreads();
    const int m = tid & 15, bc = tid >> 4;
    float v = 0.f;
#pragma unroll
    for (int w = 0; w < 8; ++w) v += red[w][m][bc];
    const float c0 = a[0], c1 = a[1], c2 = a[2], c3 = a[3], c4 = a[4];
    const size_t idx = (size_t)bc * 4096 + m0 + m;
    g2b[idx] = (__bf16)(c0 * x[idx] + c1 * (float)z1b[idx] + c2 * (float)z2b[idx]
                        + c3 * (float)z3b[idx] + c4 * v);
}

// h0 = g2 @ w_map: grid 16 (btile x hp), 512 thr = 8 waves x 512-K, plain stores.
__global__ __launch_bounds__(512) void map_gemm_kernel(
    const __bf16* __restrict__ g2b, const __bf16* __restrict__ w_mapT,
    float* __restrict__ h0)
{
    __shared__ float red[8][16][33];
    const int bi = blockIdx.x, tid = threadIdx.x;
    const int wave = tid >> 6, lane = tid & 63;
    const int l15 = lane & 15, q = lane >> 4;
    const int btile = bi & 1, hp = bi >> 1;
    const int kbase = wave * 512 + q * 8;

    const __bf16* ap  = g2b + (size_t)(btile * 16 + l15) * 4096 + kbase;
    const __bf16* bp0 = w_mapT + (size_t)(hp * 32 + l15) * 4096 + kbase;
    const __bf16* bp1 = w_mapT + (size_t)(hp * 32 + 16 + l15) * 4096 + kbase;

    bf16x8 ab[4], b0b[4], b1b[4];
    f32x4 acc0 = {0,0,0,0}, acc1 = {0,0,0,0};
#pragma unroll
    for (int s = 0; s < 3; ++s) {
        const int k = s * 32;
        ab[s]  = *(const bf16x8*)(ap + k);
        b0b[s] = *(const bf16x8*)(bp0 + k);
        b1b[s] = *(const bf16x8*)(bp1 + k);
    }
#pragma unroll
    for (int s = 0; s < 16; ++s) {
        const int cur = s & 3;
        if (s < 13) {
            const int nxt = (s + 3) & 3;
            const int kn = (s + 3) * 32;
            ab[nxt]  = *(const bf16x8*)(ap + kn);
            b0b[nxt] = *(const bf16x8*)(bp0 + kn);
            b1b[nxt] = *(const bf16x8*)(bp1 + kn);
        }
        acc0 = mfma16(ab[cur], b0b[cur], acc0);
        acc1 = mfma16(ab[cur], b1b[cur], acc1);
    }
#pragma unroll
    for (int r = 0; r < 4; ++r) {
        const int mr = q * 4 + r;
        red[wave][mr][l15]      = acc0[r];
        red[wave][mr][l15 + 16] = acc1[r];
    }
    __syncthreads();
    const int m = tid >> 5, hcol = tid & 31;
    float v = 0.f;
#pragma unroll
    for (int w = 0; w < 8; ++w) v += red[w][m][hcol];
    h0[(size_t)(btile * 16 + m) * 256 + hp * 32 + hcol] = v;
}

// ResNet_FC + head to u (bf16). 1024 thr: col=tid&255, kg=tid>>8.
__global__ __launch_bounds__(1024) void resnet_kernel(
    const float* __restrict__ h0, const float* __restrict__ b_map,
    const float* __restrict__ res_w, const float* __restrict__ res_b,
    const float* __restrict__ t_out, const float* __restrict__ w_o1,
    const float* __restrict__ b_o1, __bf16* __restrict__ u_b)
{
    __shared__ float zs[256];
    __shared__ float part[4][256];
    const int b = blockIdx.x, tid = threadIdx.x;
    const int col = tid & 255, kg = tid >> 8;

    float hv = 0.f;
    if (kg == 0) {
        hv = h0[b * 256 + col] + b_map[col];
        zs[col] = hv;
    }
    __syncthreads();

#pragma unroll
    for (int r = 0; r < 2; ++r) {
        for (int i = 0; i < 3; ++i) {
            part[kg][col] = dotW<4>(res_w + ((size_t)(r * 3 + i) << 16) + (size_t)kg * 64 * 256,
                                    zs + kg * 64, col);
            __syncthreads();
            if (kg == 0) {
                zs[col] = silu_f(res_b[(r * 3 + i) * 256 + col]
                                 + part[0][col] + part[1][col] + part[2][col] + part[3][col]);
            }
            __syncthreads();
        }
        if (kg == 0) {
            hv = (hv + zs[col]) * 0.70710678118654752f;
            zs[col] = hv;
        }
        __syncthreads();
    }

    if (kg == 0) zs[col] = hv + t_out[b * 256 + col];
    __syncthreads();
    part[kg][col] = dotW<4>(w_o1 + (size_t)kg * 64 * 256, zs + kg * 64, col);
    __syncthreads();
    if (kg == 0) {
        u_b[b * 256 + col] = (__bf16)silu_f(b_o1[col]
            + part[0][col] + part[1][col] + part[2][col] + part[3][col]);
    }
}

// out[b,n] = sum_h u[b,h] * w_o2[h,n] + b_o2[n]   (K=256, full-K per wave)
__global__ __launch_bounds__(256) void out_gemm_kernel(
    const __bf16* __restrict__ u_b, const __bf16* __restrict__ w_o2T,
    const float* __restrict__ b_o2, float* __restrict__ out)
{
    const int tid = threadIdx.x;
    const int wave = tid >> 6, lane = tid & 63;
    const int l15 = lane & 15, q = lane >> 4;
    const int g = blockIdx.x * 4 + wave;
    const int btile = g & 1;
    const int n0 = (g >> 1) * 32;

    const __bf16* ap  = u_b + (size_t)(btile * 16 + l15) * 256;
    const __bf16* bp0 = w_o2T + (size_t)(n0 + l15) * 256;
    const __bf16* bp1 = w_o2T + (size_t)(n0 + 16 + l15) * 256;

    f32x4 acc0 = {0,0,0,0}, acc1 = {0,0,0,0};
#pragma unroll
    for (int ks = 0; ks < 8; ++ks) {
        const int k = ks * 32 + q * 8;
        bf16x8 a  = *(const bf16x8*)(ap + k);
        bf16x8 b0 = *(const bf16x8*)(bp0 + k);
        bf16x8 b1 = *(const bf16x8*)(bp1 + k);
        acc0 = mfma16(a, b0, acc0);
        acc1 = mfma16(a, b1, acc1);
    }
    const int row = btile * 16 + q * 4;
    const int na = n0 + l15, nb = n0 + 16 + l15;
#pragma unroll
    for (int r = 0; r < 4; ++r) {
        out[(size_t)(row + r) * 4096 + na] = acc0[r] + b_o2[na];
        out[(size_t)(row + r) * 4096 + nb] = acc1[r] + b_o2[nb];
    }
}

extern "C" void kernel_launch(void* const* d_in, const int* in_sizes, int n_in,
                              void* d_out, int out_size, void* d_ws, size_t ws_size,
                              hipStream_t stream)
{
    (void)in_sizes; (void)n_in; (void)out_size; (void)ws_size;
    const float* x     = (const float*)d_in[0];
    const float* t     = (const float*)d_in[1];
    const float* L     = (const float*)d_in[2];
    const float* w_g1  = (const float*)d_in[3];
    const float* w_g2  = (const float*)d_in[4];
    const float* w_t1  = (const float*)d_in[5];
    const float* b_t1  = (const float*)d_in[6];
    const float* w_t2  = (const float*)d_in[7];
    const float* b_t2  = (const float*)d_in[8];
    const float* w_map = (const float*)d_in[9];
    const float* b_map = (const float*)d_in[10];
    const float* res_w = (const float*)d_in[11];
    const float* res_b = (const float*)d_in[12];
    const float* w_o1  = (const float*)d_in[13];
    const float* b_o1  = (const float*)d_in[14];
    const float* w_o2  = (const float*)d_in[15];
    const float* b_o2  = (const float*)d_in[16];
    float* out = (float*)d_out;
    char* ws = (char*)d_ws;

    float* a_c  = (float*)(ws + WS_A);
    float* tout = (float*)(ws + WS_TOUT);
    __bf16* z1b = (__bf16*)(ws + WS_ZB);
    __bf16* z2b = (__bf16*)(ws + WS_ZB + WS_ZSTR);
    __bf16* z3b = (__bf16*)(ws + WS_ZB + 2 * WS_ZSTR);
    __bf16* g2b = (__bf16*)(ws + WS_G2B);
    float* h0   = (float*)(ws + WS_H0);
    __bf16* u_b    = (__bf16*)(ws + WS_UB);
    __bf16* w_mapT = (__bf16*)(ws + WS_WMAPT);
    __bf16* w_o2T  = (__bf16*)(ws + WS_WO2T);
    __bf16* Lb     = (__bf16*)(ws + WS_LBF);

    prep_kernel<<<2081, 256, 0, stream>>>(t, w_g1, w_g2, w_t1, b_t1, w_t2, b_t2,
                                          w_map, w_o2, ws);
    hop1_kernel<<<256, 512, 0, stream>>>(L, x, Lb, z1b);
    hop_kernel<<<256, 512, 0, stream>>>(Lb, z1b, z2b);
    hop_kernel<<<256, 512, 0, stream>>>(Lb, z2b, z3b);
    hop_final_kernel<<<256, 512, 0, stream>>>(Lb, z3b, x, z1b, z2b, a_c, g2b);
    map_gemm_kernel<<<16, 512, 0, stream>>>(g2b, w_mapT, h0);
    resnet_kernel<<<32, 1024, 0, stream>>>(h0, b_map, res_w, res_b, tout, w_o1, b_o1, u_b);
    out_gemm_kernel<<<64, 256, 0, stream>>>(u_b, w_o2T, b_o2, out);
}